// Round 6
// baseline (104.541 us; speedup 1.0000x reference)
//
#include <hip/hip_runtime.h>
#include <hip/hip_bf16.h>
#include <hip/hip_fp16.h>
#include <math.h>

// B=4096, D=768, K=60. Output: scalar fp32 mean CE loss, label 0.
// loss_b = logsumexp(logits_b) - logits_b[0].
//
// Phases (no same-address atomics, no barriers in the hot phase):
//   1. convert user+items fp32 -> fp16 (packed) into ws
//   2. gather_dots: one wave per 8 logits (8 waves/row, 32768 waves),
//      v_dot2_f32_f16 inner product, 16 gather loads in flight/wave,
//      butterfly-fold reduction (8 accs -> lanes 0..7 in ~34 ops)
//   3. lse_loss: one wave per row -> per-row loss
//   4. final_reduce: one block -> mean into d_out
//
// ws layout:
//   [0, 1MB)        logits (4096 x 64 fp32; 61 real + 3 dummy)
//   [+1MB, +6.29MB) items fp16 (4096 x 768)
//   [+,    +6.29MB) user  fp16 (4096 x 768)
//   [+, +16KB)      per-row loss (4096 fp32)

#define NB 4096
#define ND 768
#define NK 60
#define ND4  (ND / 4)          // 192 float4 per fp32 row
#define NDU  (ND / 2)          // 384 uints per fp16 row
#define NLOGITS (NK + 1)       // 61
#define NPAD 64

#define WS_LOGITS_OFF 0
#define WS_ITEMS_OFF  ((size_t)NB * NPAD * 4)                   // 1 MB
#define WS_USER_OFF   (WS_ITEMS_OFF + (size_t)NB * ND * 2)      // +6.29 MB
#define WS_LOSS_OFF   (WS_USER_OFF + (size_t)NB * ND * 2)       // +6.29 MB
#define WS_NEED       (WS_LOSS_OFF + (size_t)NB * 4)

typedef _Float16 h2 __attribute__((ext_vector_type(2)));
typedef float    f2 __attribute__((ext_vector_type(2)));

__device__ __forceinline__ float dot2_acc(unsigned int u, unsigned int v, float c) {
#if __has_builtin(__builtin_amdgcn_fdot2)
    return __builtin_amdgcn_fdot2(__builtin_bit_cast(h2, u),
                                  __builtin_bit_cast(h2, v), c, false);
#else
    f2 a = __builtin_convertvector(__builtin_bit_cast(h2, u), f2);
    f2 b = __builtin_convertvector(__builtin_bit_cast(h2, v), f2);
    return c + a.x * b.x + a.y * b.y;
#endif
}

// ---- phase 1: both tables fp32 -> fp16 (packed uint2 = 4 halves) ----
__global__ __launch_bounds__(256) void convert_f16(
    const float4* __restrict__ user, const float4* __restrict__ items,
    uint2* __restrict__ userh, uint2* __restrict__ itemsh)
{
    int i = blockIdx.x * 256 + threadIdx.x;
    float4 u = user[i];
    float4 v = items[i];
    h2 ua = { (_Float16)u.x, (_Float16)u.y };
    h2 ub = { (_Float16)u.z, (_Float16)u.w };
    h2 va = { (_Float16)v.x, (_Float16)v.y };
    h2 vb = { (_Float16)v.z, (_Float16)v.w };
    uint2 ru, rv;
    ru.x = __builtin_bit_cast(unsigned int, ua);
    ru.y = __builtin_bit_cast(unsigned int, ub);
    rv.x = __builtin_bit_cast(unsigned int, va);
    rv.y = __builtin_bit_cast(unsigned int, vb);
    userh[i]  = ru;
    itemsh[i] = rv;
}

// ---- phase 2: one wave per 8 logits; 8 waves per row ----
__global__ __launch_bounds__(256, 4) void gather_dots(
    const unsigned int* __restrict__ userh,
    const unsigned int* __restrict__ itemsh,
    const int* __restrict__ negidx,
    float* __restrict__ logits)
{
    const int tid  = threadIdx.x;
    const int lane = tid & 63;
    const int w    = blockIdx.x * 4 + (tid >> 6);   // global wave id
    const int b    = w >> 3;                        // row
    const int slot = w & 7;                         // 8 logits per slot

    // 8 row indices (wave-uniform -> scalar loads)
    const int* nrow = negidx + (size_t)b * NK;
    int rows[8];
    #pragma unroll
    for (int i = 0; i < 8; ++i) {
        int k = slot * 8 + i;
        rows[i] = (k == 0 || k > NK) ? b : nrow[k - 1];
    }

    // user row fp16: uint4 (halves 8l..8l+7) + uint2 (halves 512+4l..4l+3)
    const unsigned int* ur = userh + (size_t)b * NDU;
    uint4 ua = ((const uint4*)ur)[lane];
    uint2 ub = ((const uint2*)(ur + 256))[lane];

    // 16 gather loads in flight (launch_bounds(256,4) leaves VGPR room)
    uint4 va[8];
    uint2 vb[8];
    #pragma unroll
    for (int i = 0; i < 8; ++i) {
        const unsigned int* ir = itemsh + (size_t)rows[i] * NDU;
        va[i] = ((const uint4*)ir)[lane];
        vb[i] = ((const uint2*)(ir + 256))[lane];
    }

    float acc[8];
    #pragma unroll
    for (int i = 0; i < 8; ++i) {
        float a = 0.0f;
        a = dot2_acc(ua.x, va[i].x, a);
        a = dot2_acc(ua.y, va[i].y, a);
        a = dot2_acc(ua.z, va[i].z, a);
        a = dot2_acc(ua.w, va[i].w, a);
        a = dot2_acc(ub.x, vb[i].x, a);
        a = dot2_acc(ub.y, vb[i].y, a);
        acc[i] = a;
    }

    // Butterfly fold: 8 accs -> each lane holds full sum of logit (lane&7).
    // Step 1 (xor 1): 8 -> 4
    const int bit0 = lane & 1;
    float n[4];
    #pragma unroll
    for (int j = 0; j < 4; ++j) {
        float mine  = bit0 ? acc[2*j+1] : acc[2*j];
        float other = bit0 ? acc[2*j]   : acc[2*j+1];
        n[j] = mine + __shfl_xor(other, 1, 64);
    }
    // Step 2 (xor 2): 4 -> 2
    const int bit1 = (lane >> 1) & 1;
    float s[2];
    #pragma unroll
    for (int j = 0; j < 2; ++j) {
        float mine  = bit1 ? n[2*j+1] : n[2*j];
        float other = bit1 ? n[2*j]   : n[2*j+1];
        s[j] = mine + __shfl_xor(other, 2, 64);
    }
    // Step 3 (xor 4): 2 -> 1
    const int bit2 = (lane >> 2) & 1;
    {
        float mine  = bit2 ? s[1] : s[0];
        float other = bit2 ? s[0] : s[1];
        float r = mine + __shfl_xor(other, 4, 64);
        // Fold over remaining lane groups
        r += __shfl_xor(r, 8, 64);
        r += __shfl_xor(r, 16, 64);
        r += __shfl_xor(r, 32, 64);
        // Lanes 0..7 hold logits slot*8 + 0..7
        if (lane < 8)
            logits[(size_t)b * NPAD + slot * 8 + lane] = r;
    }
}

// ---- phase 3: one wave per row: logsumexp -> per-row loss ----
__global__ __launch_bounds__(256) void lse_loss(
    const float* __restrict__ logits, float* __restrict__ loss)
{
    const int tid  = threadIdx.x;
    const int lane = tid & 63;
    const int b    = blockIdx.x * 4 + (tid >> 6);

    float v  = (lane < NLOGITS) ? logits[(size_t)b * NPAD + lane] : -INFINITY;
    float p0 = __shfl(v, 0, 64);
    float m = v;
    #pragma unroll
    for (int off = 32; off > 0; off >>= 1)
        m = fmaxf(m, __shfl_down(m, off, 64));
    m = __shfl(m, 0, 64);
    float e = (lane < NLOGITS) ? __expf(v - m) : 0.0f;
    #pragma unroll
    for (int off = 32; off > 0; off >>= 1)
        e += __shfl_down(e, off, 64);
    if (lane == 0)
        loss[b] = m + __logf(e) - p0;
}

// ---- phase 4: single block reduces 4096 losses -> mean ----
__global__ __launch_bounds__(256) void final_reduce(
    const float* __restrict__ loss, float* __restrict__ out)
{
    const int tid = threadIdx.x;
    const float4* l4 = (const float4*)loss;   // 1024 float4
    float s = 0.0f;
    #pragma unroll
    for (int j = 0; j < 4; ++j) {
        float4 v = l4[tid + 256 * j];
        s += v.x + v.y + v.z + v.w;
    }
    #pragma unroll
    for (int off = 32; off > 0; off >>= 1)
        s += __shfl_down(s, off, 64);
    __shared__ float ps[4];
    if ((tid & 63) == 0) ps[tid >> 6] = s;
    __syncthreads();
    if (tid == 0)
        out[0] = (ps[0] + ps[1] + ps[2] + ps[3]) * (1.0f / (float)NB);
}

// ---- fallback (fp32 single-kernel path) if ws too small ----
__global__ __launch_bounds__(256) void u2i_loss_f32(
    const float* __restrict__ user,
    const float* __restrict__ items,
    const int* __restrict__ negidx,
    float* __restrict__ out)
{
    const int b    = blockIdx.x;
    const int tid  = threadIdx.x;
    const int wave = tid >> 6;
    const int lane = tid & 63;

    __shared__ int   rows_s[NPAD];
    __shared__ float logits[NPAD];

    if (tid < NPAD) {
        const int* nrow = negidx + (size_t)b * NK;
        rows_s[tid] = (tid == 0 || tid > NK) ? b : nrow[tid - 1];
    }
    const float4* u4 = (const float4*)user + (size_t)b * ND4;
    float4 u0 = u4[lane];
    float4 u1 = u4[64 + lane];
    float4 u2 = u4[128 + lane];
    __syncthreads();

    const float4* it4 = (const float4*)items;
    #pragma unroll
    for (int j = 0; j < 4; ++j) {
        int ks[4];
        const float4* p[4];
        #pragma unroll
        for (int i = 0; i < 4; ++i) {
            ks[i] = wave + j * 16 + i * 4;
            p[i]  = it4 + (size_t)rows_s[ks[i]] * ND4;
        }
        float4 v0[4], v1[4], v2[4];
        #pragma unroll
        for (int i = 0; i < 4; ++i) {
            v0[i] = p[i][lane];
            v1[i] = p[i][64 + lane];
            v2[i] = p[i][128 + lane];
        }
        float acc[4];
        #pragma unroll
        for (int i = 0; i < 4; ++i) {
            float a;
            a  = u0.x * v0[i].x + u0.y * v0[i].y + u0.z * v0[i].z + u0.w * v0[i].w;
            a += u1.x * v1[i].x + u1.y * v1[i].y + u1.z * v1[i].z + u1.w * v1[i].w;
            a += u2.x * v2[i].x + u2.y * v2[i].y + u2.z * v2[i].z + u2.w * v2[i].w;
            acc[i] = a;
        }
        #pragma unroll
        for (int off = 32; off > 0; off >>= 1) {
            #pragma unroll
            for (int i = 0; i < 4; ++i)
                acc[i] += __shfl_down(acc[i], off, 64);
        }
        if (lane == 0) {
            #pragma unroll
            for (int i = 0; i < 4; ++i)
                logits[ks[i]] = acc[i];
        }
    }
    __syncthreads();

    if (tid < 64) {
        float v = (tid < NLOGITS) ? logits[tid] : -INFINITY;
        float m = v;
        #pragma unroll
        for (int off = 32; off > 0; off >>= 1)
            m = fmaxf(m, __shfl_down(m, off, 64));
        m = __shfl(m, 0, 64);
        float e = (tid < NLOGITS) ? __expf(v - m) : 0.0f;
        #pragma unroll
        for (int off = 32; off > 0; off >>= 1)
            e += __shfl_down(e, off, 64);
        if (tid == 0) {
            float loss = m + __logf(e) - logits[0];
            atomicAdd(out, loss * (1.0f / (float)NB));
        }
    }
}

extern "C" void kernel_launch(void* const* d_in, const int* in_sizes, int n_in,
                              void* d_out, int out_size, void* d_ws, size_t ws_size,
                              hipStream_t stream) {
    const float* user  = (const float*)d_in[0];   // (B, D) fp32
    const float* items = (const float*)d_in[1];   // (B, D) fp32
    const int*   negi  = (const int*)d_in[2];     // (B, K) int32
    float* out = (float*)d_out;                   // scalar fp32

    if (ws_size >= WS_NEED) {
        char* ws = (char*)d_ws;
        float* logits = (float*)(ws + WS_LOGITS_OFF);
        uint2* itemsh = (uint2*)(ws + WS_ITEMS_OFF);
        uint2* userh  = (uint2*)(ws + WS_USER_OFF);
        float* loss   = (float*)(ws + WS_LOSS_OFF);

        convert_f16<<<(NB * ND / 4) / 256, 256, 0, stream>>>(
            (const float4*)user, (const float4*)items, userh, itemsh);
        gather_dots<<<NB * 8 / 4, 256, 0, stream>>>(
            (const unsigned int*)userh, (const unsigned int*)itemsh, negi, logits);
        lse_loss<<<NB / 4, 256, 0, stream>>>(logits, loss);
        final_reduce<<<1, 256, 0, stream>>>(loss, out);
    } else {
        hipMemsetAsync(out, 0, sizeof(float), stream);
        u2i_loss_f32<<<NB, 256, 0, stream>>>(user, items, negi, out);
    }
}

// Round 7
// 102.873 us; speedup vs baseline: 1.0162x; 1.0162x over previous
//
#include <hip/hip_runtime.h>
#include <hip/hip_bf16.h>
#include <hip/hip_fp16.h>
#include <math.h>

// B=4096, D=768, K=60. Output: scalar fp32 mean CE loss, label 0.
// loss_b = logsumexp(logits_b) - logits_b[0].
//
// Phases:
//   1. convert ITEMS ONLY fp32 -> fp16 into ws (12.6 MB read, 6.3 MB write)
//   2. gather_dots: one wave per 8 logits (8 waves/row, 32768 waves);
//      user row loaded fp32 + converted to packed halves in-register once
//      per wave; inner loop is pure v_dot2_f32_f16; 16 gather loads in flight
//   3. lse_loss: one wave per row -> per-row loss
//   4. final_reduce: one block -> mean into d_out
//
// ws layout:
//   [0, 1MB)        logits (4096 x 64 fp32; 61 real + 3 dummy)
//   [+1MB, +6.29MB) items fp16 (4096 x 768)
//   [+, +16KB)      per-row loss (4096 fp32)

#define NB 4096
#define ND 768
#define NK 60
#define ND4  (ND / 4)          // 192 float4 per fp32 row
#define NDU  (ND / 2)          // 384 uints per fp16 row
#define NLOGITS (NK + 1)       // 61
#define NPAD 64

#define WS_LOGITS_OFF 0
#define WS_ITEMS_OFF  ((size_t)NB * NPAD * 4)                   // 1 MB
#define WS_LOSS_OFF   (WS_ITEMS_OFF + (size_t)NB * ND * 2)      // +6.29 MB
#define WS_NEED       (WS_LOSS_OFF + (size_t)NB * 4)

typedef _Float16 h2 __attribute__((ext_vector_type(2)));
typedef float    f2 __attribute__((ext_vector_type(2)));

__device__ __forceinline__ float dot2_acc(unsigned int u, unsigned int v, float c) {
#if __has_builtin(__builtin_amdgcn_fdot2)
    return __builtin_amdgcn_fdot2(__builtin_bit_cast(h2, u),
                                  __builtin_bit_cast(h2, v), c, false);
#else
    f2 a = __builtin_convertvector(__builtin_bit_cast(h2, u), f2);
    f2 b = __builtin_convertvector(__builtin_bit_cast(h2, v), f2);
    return c + a.x * b.x + a.y * b.y;
#endif
}

__device__ __forceinline__ unsigned int pack_h2(float x, float y) {
    h2 h = { (_Float16)x, (_Float16)y };
    return __builtin_bit_cast(unsigned int, h);
}

// ---- phase 1: items fp32 -> fp16 (packed uint2 = 4 halves) ----
__global__ __launch_bounds__(256) void convert_items_f16(
    const float4* __restrict__ items, uint2* __restrict__ itemsh)
{
    int i = blockIdx.x * 256 + threadIdx.x;
    float4 v = items[i];
    uint2 rv;
    rv.x = pack_h2(v.x, v.y);
    rv.y = pack_h2(v.z, v.w);
    itemsh[i] = rv;
}

// ---- phase 2: one wave per 8 logits; 8 waves per row ----
__global__ __launch_bounds__(256, 4) void gather_dots(
    const float* __restrict__ user,
    const unsigned int* __restrict__ itemsh,
    const int* __restrict__ negidx,
    float* __restrict__ logits)
{
    const int tid  = threadIdx.x;
    const int lane = tid & 63;
    const int w    = blockIdx.x * 4 + (tid >> 6);   // global wave id
    const int b    = w >> 3;                        // row
    const int slot = w & 7;                         // 8 logits per slot

    // 8 row indices (wave-uniform -> scalar loads)
    const int* nrow = negidx + (size_t)b * NK;
    int rows[8];
    #pragma unroll
    for (int i = 0; i < 8; ++i) {
        int k = slot * 8 + i;
        rows[i] = (k == 0 || k > NK) ? b : nrow[k - 1];
    }

    // user row fp32 -> packed halves in-register, matching the item layout:
    //   ua.{x,y,z,w} = halves of elements 8l..8l+7
    //   ub.{x,y}     = halves of elements 512+4l..512+4l+3
    const float4* ur4 = (const float4*)(user + (size_t)b * ND);
    float4 uf0 = ur4[2 * lane];        // elements 8l..8l+3
    float4 uf1 = ur4[2 * lane + 1];    // elements 8l+4..8l+7
    float4 uf2 = ur4[128 + lane];      // elements 512+4l..512+4l+3
    uint4 ua;
    ua.x = pack_h2(uf0.x, uf0.y);
    ua.y = pack_h2(uf0.z, uf0.w);
    ua.z = pack_h2(uf1.x, uf1.y);
    ua.w = pack_h2(uf1.z, uf1.w);
    uint2 ub;
    ub.x = pack_h2(uf2.x, uf2.y);
    ub.y = pack_h2(uf2.z, uf2.w);

    // 16 gather loads in flight
    uint4 va[8];
    uint2 vb[8];
    #pragma unroll
    for (int i = 0; i < 8; ++i) {
        const unsigned int* ir = itemsh + (size_t)rows[i] * NDU;
        va[i] = ((const uint4*)ir)[lane];
        vb[i] = ((const uint2*)(ir + 256))[lane];
    }

    float acc[8];
    #pragma unroll
    for (int i = 0; i < 8; ++i) {
        float a = 0.0f;
        a = dot2_acc(ua.x, va[i].x, a);
        a = dot2_acc(ua.y, va[i].y, a);
        a = dot2_acc(ua.z, va[i].z, a);
        a = dot2_acc(ua.w, va[i].w, a);
        a = dot2_acc(ub.x, vb[i].x, a);
        a = dot2_acc(ub.y, vb[i].y, a);
        acc[i] = a;
    }

    // Butterfly fold: 8 accs -> each lane holds full sum of logit (lane&7).
    const int bit0 = lane & 1;
    float n[4];
    #pragma unroll
    for (int j = 0; j < 4; ++j) {
        float mine  = bit0 ? acc[2*j+1] : acc[2*j];
        float other = bit0 ? acc[2*j]   : acc[2*j+1];
        n[j] = mine + __shfl_xor(other, 1, 64);
    }
    const int bit1 = (lane >> 1) & 1;
    float s[2];
    #pragma unroll
    for (int j = 0; j < 2; ++j) {
        float mine  = bit1 ? n[2*j+1] : n[2*j];
        float other = bit1 ? n[2*j]   : n[2*j+1];
        s[j] = mine + __shfl_xor(other, 2, 64);
    }
    const int bit2 = (lane >> 2) & 1;
    {
        float mine  = bit2 ? s[1] : s[0];
        float other = bit2 ? s[0] : s[1];
        float r = mine + __shfl_xor(other, 4, 64);
        r += __shfl_xor(r, 8, 64);
        r += __shfl_xor(r, 16, 64);
        r += __shfl_xor(r, 32, 64);
        if (lane < 8)
            logits[(size_t)b * NPAD + slot * 8 + lane] = r;
    }
}

// ---- phase 3: one wave per row: logsumexp -> per-row loss ----
__global__ __launch_bounds__(256) void lse_loss(
    const float* __restrict__ logits, float* __restrict__ loss)
{
    const int tid  = threadIdx.x;
    const int lane = tid & 63;
    const int b    = blockIdx.x * 4 + (tid >> 6);

    float v  = (lane < NLOGITS) ? logits[(size_t)b * NPAD + lane] : -INFINITY;
    float p0 = __shfl(v, 0, 64);
    float m = v;
    #pragma unroll
    for (int off = 32; off > 0; off >>= 1)
        m = fmaxf(m, __shfl_down(m, off, 64));
    m = __shfl(m, 0, 64);
    float e = (lane < NLOGITS) ? __expf(v - m) : 0.0f;
    #pragma unroll
    for (int off = 32; off > 0; off >>= 1)
        e += __shfl_down(e, off, 64);
    if (lane == 0)
        loss[b] = m + __logf(e) - p0;
}

// ---- phase 4: single block reduces 4096 losses -> mean ----
__global__ __launch_bounds__(256) void final_reduce(
    const float* __restrict__ loss, float* __restrict__ out)
{
    const int tid = threadIdx.x;
    const float4* l4 = (const float4*)loss;   // 1024 float4
    float s = 0.0f;
    #pragma unroll
    for (int j = 0; j < 4; ++j) {
        float4 v = l4[tid + 256 * j];
        s += v.x + v.y + v.z + v.w;
    }
    #pragma unroll
    for (int off = 32; off > 0; off >>= 1)
        s += __shfl_down(s, off, 64);
    __shared__ float ps[4];
    if ((tid & 63) == 0) ps[tid >> 6] = s;
    __syncthreads();
    if (tid == 0)
        out[0] = (ps[0] + ps[1] + ps[2] + ps[3]) * (1.0f / (float)NB);
}

// ---- fallback (fp32 single-kernel path) if ws too small ----
__global__ __launch_bounds__(256) void u2i_loss_f32(
    const float* __restrict__ user,
    const float* __restrict__ items,
    const int* __restrict__ negidx,
    float* __restrict__ out)
{
    const int b    = blockIdx.x;
    const int tid  = threadIdx.x;
    const int wave = tid >> 6;
    const int lane = tid & 63;

    __shared__ int   rows_s[NPAD];
    __shared__ float logits[NPAD];

    if (tid < NPAD) {
        const int* nrow = negidx + (size_t)b * NK;
        rows_s[tid] = (tid == 0 || tid > NK) ? b : nrow[tid - 1];
    }
    const float4* u4 = (const float4*)user + (size_t)b * ND4;
    float4 u0 = u4[lane];
    float4 u1 = u4[64 + lane];
    float4 u2 = u4[128 + lane];
    __syncthreads();

    const float4* it4 = (const float4*)items;
    #pragma unroll
    for (int j = 0; j < 4; ++j) {
        int ks[4];
        const float4* p[4];
        #pragma unroll
        for (int i = 0; i < 4; ++i) {
            ks[i] = wave + j * 16 + i * 4;
            p[i]  = it4 + (size_t)rows_s[ks[i]] * ND4;
        }
        float4 v0[4], v1[4], v2[4];
        #pragma unroll
        for (int i = 0; i < 4; ++i) {
            v0[i] = p[i][lane];
            v1[i] = p[i][64 + lane];
            v2[i] = p[i][128 + lane];
        }
        float acc[4];
        #pragma unroll
        for (int i = 0; i < 4; ++i) {
            float a;
            a  = u0.x * v0[i].x + u0.y * v0[i].y + u0.z * v0[i].z + u0.w * v0[i].w;
            a += u1.x * v1[i].x + u1.y * v1[i].y + u1.z * v1[i].z + u1.w * v1[i].w;
            a += u2.x * v2[i].x + u2.y * v2[i].y + u2.z * v2[i].z + u2.w * v2[i].w;
            acc[i] = a;
        }
        #pragma unroll
        for (int off = 32; off > 0; off >>= 1) {
            #pragma unroll
            for (int i = 0; i < 4; ++i)
                acc[i] += __shfl_down(acc[i], off, 64);
        }
        if (lane == 0) {
            #pragma unroll
            for (int i = 0; i < 4; ++i)
                logits[ks[i]] = acc[i];
        }
    }
    __syncthreads();

    if (tid < 64) {
        float v = (tid < NLOGITS) ? logits[tid] : -INFINITY;
        float m = v;
        #pragma unroll
        for (int off = 32; off > 0; off >>= 1)
            m = fmaxf(m, __shfl_down(m, off, 64));
        m = __shfl(m, 0, 64);
        float e = (tid < NLOGITS) ? __expf(v - m) : 0.0f;
        #pragma unroll
        for (int off = 32; off > 0; off >>= 1)
            e += __shfl_down(e, off, 64);
        if (tid == 0) {
            float loss = m + __logf(e) - logits[0];
            atomicAdd(out, loss * (1.0f / (float)NB));
        }
    }
}

extern "C" void kernel_launch(void* const* d_in, const int* in_sizes, int n_in,
                              void* d_out, int out_size, void* d_ws, size_t ws_size,
                              hipStream_t stream) {
    const float* user  = (const float*)d_in[0];   // (B, D) fp32
    const float* items = (const float*)d_in[1];   // (B, D) fp32
    const int*   negi  = (const int*)d_in[2];     // (B, K) int32
    float* out = (float*)d_out;                   // scalar fp32

    if (ws_size >= WS_NEED) {
        char* ws = (char*)d_ws;
        float* logits = (float*)(ws + WS_LOGITS_OFF);
        uint2* itemsh = (uint2*)(ws + WS_ITEMS_OFF);
        float* loss   = (float*)(ws + WS_LOSS_OFF);

        // 786432 float4 -> 3072 blocks of 256
        convert_items_f16<<<(NB * ND / 4) / 256, 256, 0, stream>>>(
            (const float4*)items, itemsh);
        // 4096 rows x 8 waves = 32768 waves = 8192 blocks of 4 waves
        gather_dots<<<NB * 8 / 4, 256, 0, stream>>>(
            user, (const unsigned int*)itemsh, negi, logits);
        lse_loss<<<NB / 4, 256, 0, stream>>>(logits, loss);
        final_reduce<<<1, 256, 0, stream>>>(loss, out);
    } else {
        hipMemsetAsync(out, 0, sizeof(float), stream);
        u2i_loss_f32<<<NB, 256, 0, stream>>>(user, items, negi, out);
    }
}